// Round 10
// baseline (569.088 us; speedup 1.0000x reference)
//
#include <hip/hip_runtime.h>
#include <math.h>

#define T 1024
#define FS 132   // feature row stride (floats)
#define FSQ 33   // in float4
#define AS 68    // scratch row stride

typedef __attribute__((ext_vector_type(8)))  short short8;
typedef __attribute__((ext_vector_type(4)))  float f32x4;
typedef __attribute__((ext_vector_type(16))) float f32x16;
typedef __attribute__((ext_vector_type(4)))  unsigned u32x4;
typedef __attribute__((ext_vector_type(2)))  unsigned u32x2;

__device__ __forceinline__ void fma4(float4& a, float s, const float4 b) {
  a.x = fmaf(s, b.x, a.x);
  a.y = fmaf(s, b.y, a.y);
  a.z = fmaf(s, b.z, a.z);
  a.w = fmaf(s, b.w, a.w);
}
__device__ __forceinline__ unsigned bf16rne(float f) {
  unsigned u = __float_as_uint(f);
  return (u + 0x7FFFu + ((u >> 16) & 1u)) >> 16;
}
// RNE 3-way split (R7/R8-validated): x ~= h + m + l, error class ~2^-26
__device__ __forceinline__ void split3(float4 a, float4 b, short8& vh, short8& vm, short8& vl) {
  const float xs[8] = {a.x, a.y, a.z, a.w, b.x, b.y, b.z, b.w};
#pragma unroll
  for (int e = 0; e < 8; ++e) {
    float x = xs[e];
    unsigned h = bf16rne(x);
    float r1 = x - __uint_as_float(h << 16);
    unsigned m = bf16rne(r1);
    float r2 = r1 - __uint_as_float(m << 16);
    unsigned l2 = bf16rne(r2);
    vh[e] = (short)h; vm[e] = (short)m; vl[e] = (short)l2;
  }
}
__device__ __forceinline__ void split2(float4 a, float4 b, short8& vh, short8& vl) {
  const float xs[8] = {a.x, a.y, a.z, a.w, b.x, b.y, b.z, b.w};
#pragma unroll
  for (int e = 0; e < 8; ++e) {
    float x = xs[e];
    unsigned h = bf16rne(x);
    float r1 = x - __uint_as_float(h << 16);
    unsigned l2 = bf16rne(r1);
    vh[e] = (short)h; vl[e] = (short)l2;
  }
}
__device__ __forceinline__ f32x16 mm32(short8 a, short8 b, f32x16 c) {
  return __builtin_amdgcn_mfma_f32_32x32x16_bf16(a, b, c, 0, 0, 0);
}
__device__ __forceinline__ f32x4 mm16(short8 a, short8 b, f32x4 c) {
  return __builtin_amdgcn_mfma_f32_16x16x32_bf16(a, b, c, 0, 0, 0);
}

__global__ __launch_bounds__(T) void gcn_ssa_kernel(
    const float* __restrict__ x,
    const float* __restrict__ wq, const float* __restrict__ bq,
    const float* __restrict__ wk, const float* __restrict__ bk,
    const float* __restrict__ wv, const float* __restrict__ bv,
    const float* __restrict__ gw1, const float* __restrict__ gb1,
    const float* __restrict__ gw2, const float* __restrict__ gb2,
    const float* __restrict__ gammap, const int* __restrict__ idxg,
    float* __restrict__ out)
{
  const int b = blockIdx.x, tid = threadIdx.x;
  const int l = tid & 63;
  const int wid = tid >> 6;
  const float* xb = x + (size_t)b * 8192;
  float* outb = out + (size_t)b * 8192;

  __shared__ __align__(16) float fq[64 * FS];
  __shared__ __align__(16) float fk[64 * FS];
  __shared__ __align__(16) float fv[64 * FS];
  __shared__ __align__(16) float U[11904];      // xT+bias | adjB/t1T/hT/gsm | kT/Pp/sc/vT
  __shared__ __align__(16) float gw1T[16 * FS]; // rows 8-15 zero; later: idx u16 staging
  __shared__ __align__(16) float gb1s[8];
  __shared__ __align__(16) float gb2s[128];
  __shared__ float rinv_s[3][64], nrm_s[3][64], rinv2_s[3][64];
  __shared__ int mte[32];

  float4* fq4 = (float4*)fq;
  float4* fk4 = (float4*)fk;
  float4* fv4 = (float4*)fv;

  // ---------------- A0: stage xT (stride 68), biases, gw1T ----------------
  {
    const float4* xg = (const float4*)xb;
    for (int i = tid; i < 2048; i += T) {
      int c = i & 63, hq = i >> 6;
      float4 v = xg[c * 32 + hq];
      int h = hq * 4;
      U[(h + 0) * AS + c] = v.x;
      U[(h + 1) * AS + c] = v.y;
      U[(h + 2) * AS + c] = v.z;
      U[(h + 3) * AS + c] = v.w;
    }
    if (tid < 192) U[8704 + tid] = (tid < 64) ? bq[tid] : (tid < 128) ? bk[tid - 64] : bv[tid - 128];
    for (int i = tid; i < 2048; i += T) {
      int j = i >> 7, h = i & 127;
      gw1T[j * FS + h] = (j < 8) ? gw1[h * 8 + j] : 0.f;
    }
    if (tid < 8) gb1s[tid] = gb1[tid];
    if (tid < 128) gb2s[tid] = gb2[tid];
  }
  __syncthreads();

  // ---------------- A1: 3 projections via MFMA 6-term (12 waves, RNE split) ----------------
  if (wid < 12) {
    const int p = wid >> 2, strip = wid & 3;
    const float* wsel = (p == 0) ? wq : (p == 1) ? wk : wv;
    float* fdst = (p == 0) ? fq : (p == 1) ? fk : fv;
    const int lr = l & 31, kg = (l >> 5) * 4;
    const int h = strip * 32 + lr;
    f32x16 acc0 = (f32x16)0.f, acc1 = (f32x16)0.f;
    for (int ks = 0; ks < 4; ++ks) {
      int kb = ks * 16;
      float4 b0 = *(const float4*)(U + h * AS + kb + kg);
      float4 b1 = *(const float4*)(U + h * AS + kb + 8 + kg);
      short8 bh, bm, bl;
      split3(b0, b1, bh, bm, bl);
      float4 a0 = *(const float4*)(wsel + lr * 64 + kb + kg);
      float4 a1 = *(const float4*)(wsel + lr * 64 + kb + 8 + kg);
      short8 ah, am, al;
      split3(a0, a1, ah, am, al);
      acc0 = mm32(ah, bh, acc0); acc0 = mm32(ah, bm, acc0); acc0 = mm32(am, bh, acc0);
      acc0 = mm32(ah, bl, acc0); acc0 = mm32(al, bh, acc0); acc0 = mm32(am, bm, acc0);
      a0 = *(const float4*)(wsel + (32 + lr) * 64 + kb + kg);
      a1 = *(const float4*)(wsel + (32 + lr) * 64 + kb + 8 + kg);
      split3(a0, a1, ah, am, al);
      acc1 = mm32(ah, bh, acc1); acc1 = mm32(ah, bm, acc1); acc1 = mm32(am, bh, acc1);
      acc1 = mm32(ah, bl, acc1); acc1 = mm32(al, bh, acc1); acc1 = mm32(am, bm, acc1);
    }
#pragma unroll
    for (int reg = 0; reg < 16; ++reg) {
      int ro = (reg & 3) + 8 * (reg >> 2) + 4 * (l >> 5);
      fdst[ro * FS + h] = acc0[reg] + U[8704 + p * 64 + ro];
      fdst[(32 + ro) * FS + h] = acc1[reg] + U[8704 + p * 64 + 32 + ro];
    }
  }
  __syncthreads();

  // ---------------- B1: row stats, all 3 branches ----------------
  {
    int row = tid >> 4, g = tid & 15;
#pragma unroll
    for (int br = 0; br < 3; ++br) {
      const float4* f4b = (br == 0) ? fq4 : (br == 1) ? fk4 : fv4;
      float4 aa = f4b[row * FSQ + 2 * g];
      float4 cc = f4b[row * FSQ + 2 * g + 1];
      float s0 = aa.x + aa.y + aa.z + aa.w + cc.x + cc.y + cc.z + cc.w;
      float s1 = aa.x * aa.x + aa.y * aa.y + aa.z * aa.z + aa.w * aa.w +
                 cc.x * cc.x + cc.y * cc.y + cc.z * cc.z + cc.w * cc.w;
      for (int off = 8; off; off >>= 1) {
        s0 += __shfl_xor(s0, off);
        s1 += __shfl_xor(s1, off);
      }
      if (g == 0) {
        rinv_s[br][row] = (s0 == 0.0f) ? 0.0f : (1.0f / s0);
        nrm_s[br][row] = 1.0f / fmaxf(sqrtf(s1), 1e-8f);
      }
    }
  }
  __syncthreads();

  unsigned short* adjw = (unsigned short*)U;   // [3][64][72] bf16 exact
  float* t1T = U + 6912;                       // [3*8][68]
  float* hT  = U + 8544;                       // [3*8][68]
  float* gsm = U + 10176;                      // [3*64][8]

  // ---------------- B2: symmetric grams (9 waves) || t1 MFMA (7 waves) — RNE ----------------
  if (wid < 9) {
    const int br = wid / 3, t3 = wid % 3;
    const float* f = (br == 0) ? fq : (br == 1) ? fk : fv;
    const int lr = l & 31, kg = (l >> 5) * 4;
    f32x16 acc = (f32x16)0.f;
    if (t3 < 2) {
      // diagonal tile: A fragment == B fragment (one split per K-step)
      const int r0 = t3 * 32;
      for (int ks = 0; ks < 8; ++ks) {
        int kb = ks * 16;
        float4 a0 = *(const float4*)(f + (r0 + lr) * FS + kb + kg);
        float4 a1 = *(const float4*)(f + (r0 + lr) * FS + kb + 8 + kg);
        short8 h, m, lo;
        split3(a0, a1, h, m, lo);
        acc = mm32(h, h, acc); acc = mm32(h, m, acc); acc = mm32(m, h, acc);
        acc = mm32(h, lo, acc); acc = mm32(lo, h, acc); acc = mm32(m, m, acc);
      }
      float nm = nrm_s[br][r0 + lr];
#pragma unroll
      for (int reg = 0; reg < 16; ++reg) {
        int rowg = r0 + (reg & 3) + 8 * (reg >> 2) + 4 * (l >> 5);
        int m = r0 + lr;
        float sim = acc[reg] * nrm_s[br][rowg] * nm;
        unsigned short e = (sim > 0.5f) ? (unsigned short)0x3F80 : (unsigned short)0;
        if (rowg == m) e = (sim > 0.5f) ? (unsigned short)0x4000 : (unsigned short)0x3F80;
        adjw[(br * 64 + rowg) * 72 + m] = e;
      }
    } else {
      // off-diagonal rows 0-31 x cols 32-63, mirrored (bit-identical to transpose tile)
      for (int ks = 0; ks < 8; ++ks) {
        int kb = ks * 16;
        float4 a0 = *(const float4*)(f + lr * FS + kb + kg);
        float4 a1 = *(const float4*)(f + lr * FS + kb + 8 + kg);
        float4 b0 = *(const float4*)(f + (32 + lr) * FS + kb + kg);
        float4 b1 = *(const float4*)(f + (32 + lr) * FS + kb + 8 + kg);
        short8 ah, am, al, bh, bm, bl;
        split3(a0, a1, ah, am, al);
        split3(b0, b1, bh, bm, bl);
        acc = mm32(ah, bh, acc); acc = mm32(ah, bm, acc); acc = mm32(am, bh, acc);
        acc = mm32(ah, bl, acc); acc = mm32(al, bh, acc); acc = mm32(am, bm, acc);
      }
      float nm = nrm_s[br][32 + lr];
#pragma unroll
      for (int reg = 0; reg < 16; ++reg) {
        int rowg = (reg & 3) + 8 * (reg >> 2) + 4 * (l >> 5);
        int m = 32 + lr;
        float sim = acc[reg] * nrm_s[br][rowg] * nm;
        unsigned short e = (sim > 0.5f) ? (unsigned short)0x3F80 : (unsigned short)0;
        adjw[(br * 64 + rowg) * 72 + m] = e;
        adjw[(br * 64 + m) * 72 + rowg] = e;
      }
    }
  } else {
    // t1: 12 tiles over 7 waves (RNE split)
    const int j15 = l & 15, kg4 = (l >> 4) * 4;
    short8 gbh[4], gbm[4], gbl[4];
#pragma unroll
    for (int ks = 0; ks < 4; ++ks) {
      int kb = ks * 32;
      float4 b0 = *(const float4*)(gw1T + j15 * FS + kb + kg4);
      float4 b1 = *(const float4*)(gw1T + j15 * FS + kb + 16 + kg4);
      split3(b0, b1, gbh[ks], gbm[ks], gbl[ks]);
    }
#pragma unroll
    for (int rep = 0; rep < 2; ++rep) {
      int t = (wid - 9) + rep * 7;
      if (t < 12) {
        int br = t >> 2, mt = t & 3;
        const float* f = (br == 0) ? fq : (br == 1) ? fk : fv;
        f32x4 acc = (f32x4)0.f;
        for (int ks = 0; ks < 4; ++ks) {
          int kb = ks * 32;
          float4 a0 = *(const float4*)(f + (mt * 16 + j15) * FS + kb + kg4);
          float4 a1 = *(const float4*)(f + (mt * 16 + j15) * FS + kb + 16 + kg4);
          short8 ah, am, al;
          split3(a0, a1, ah, am, al);
          acc = mm16(ah, gbh[ks], acc); acc = mm16(ah, gbm[ks], acc); acc = mm16(am, gbh[ks], acc);
          acc = mm16(ah, gbl[ks], acc); acc = mm16(al, gbh[ks], acc); acc = mm16(am, gbm[ks], acc);
        }
        if (j15 < 8) {
#pragma unroll
          for (int r = 0; r < 4; ++r) {
            int n = mt * 16 + (l >> 4) * 4 + r;
            t1T[(br * 8 + j15) * AS + n] = acc[r] * rinv_s[br][n];
          }
        }
      }
    }
  }
  __syncthreads();

  // ---------------- B4: in-wave adj row sums + h = relu(rinv2*(adj@t1)+gb1) ----------------
  if (tid < 768) {
    const int br = wid >> 2, mt = wid & 3;
    const int j15 = l & 15, kg4 = (l >> 4) * 4;
    float rinv2;
    {
      // rowsum of row (mt*16 + j15): 4 lanes/row (chunk = l>>4), exact small-int sums
      const unsigned short* rp = adjw + (br * 64 + mt * 16 + j15) * 72 + (l >> 4) * 16;
      u32x4 v0 = *(const u32x4*)rp;
      u32x4 v1 = *(const u32x4*)(rp + 8);
      unsigned wds[8] = {v0.x, v0.y, v0.z, v0.w, v1.x, v1.y, v1.z, v1.w};
      float s = 0.f;
#pragma unroll
      for (int e = 0; e < 8; ++e) {
        s += __uint_as_float(wds[e] << 16);
        s += __uint_as_float(wds[e] & 0xFFFF0000u);
      }
      s += __shfl_xor(s, 16);
      s += __shfl_xor(s, 32);
      rinv2 = 1.0f / s;
      if (l < 16) rinv2_s[br][mt * 16 + l] = rinv2;  // for B5
    }
    // hoist shuffles OUT of divergent region (all 64 lanes active here)
    float rv4[4];
#pragma unroll
    for (int r = 0; r < 4; ++r) rv4[r] = __shfl(rinv2, (l >> 4) * 4 + r);

    const int arow = br * 64 + mt * 16 + j15;
    f32x4 acc = (f32x4)0.f;
#pragma unroll
    for (int ks = 0; ks < 2; ++ks) {
      int kb = ks * 32;
      u32x2 lo = *(const u32x2*)(adjw + arow * 72 + kb + kg4);
      u32x2 hi = *(const u32x2*)(adjw + arow * 72 + kb + 16 + kg4);
      u32x4 cc; cc.x = lo.x; cc.y = lo.y; cc.z = hi.x; cc.w = hi.y;
      short8 af = __builtin_bit_cast(short8, cc);
      float4 b0 = *(const float4*)(t1T + (br * 8 + j15) * AS + kb + kg4);
      float4 b1 = *(const float4*)(t1T + (br * 8 + j15) * AS + kb + 16 + kg4);
      short8 bh, bm, bl;
      split3(b0, b1, bh, bm, bl);
      acc = mm16(af, bh, acc); acc = mm16(af, bm, acc); acc = mm16(af, bl, acc);
    }
    if (j15 < 8) {
      float g1 = gb1s[j15];
#pragma unroll
      for (int r = 0; r < 4; ++r) {
        int n = mt * 16 + (l >> 4) * 4 + r;
        hT[(br * 8 + j15) * AS + n] = fmaxf(fmaf(acc[r], rv4[r], g1), 0.0f);
      }
    }
  }
  __syncthreads();

  // ---------------- B5: g = rinv2*(adj@h) ----------------
  if (tid < 768) {
    const int br = wid >> 2, mt = wid & 3;
    const int j15 = l & 15, kg4 = (l >> 4) * 4;
    const int arow = br * 64 + mt * 16 + j15;
    f32x4 acc = (f32x4)0.f;
#pragma unroll
    for (int ks = 0; ks < 2; ++ks) {
      int kb = ks * 32;
      u32x2 lo = *(const u32x2*)(adjw + arow * 72 + kb + kg4);
      u32x2 hi = *(const u32x2*)(adjw + arow * 72 + kb + 16 + kg4);
      u32x4 cc; cc.x = lo.x; cc.y = lo.y; cc.z = hi.x; cc.w = hi.y;
      short8 af = __builtin_bit_cast(short8, cc);
      float4 b0 = *(const float4*)(hT + (br * 8 + j15) * AS + kb + kg4);
      float4 b1 = *(const float4*)(hT + (br * 8 + j15) * AS + kb + 16 + kg4);
      short8 bh, bm, bl;
      split3(b0, b1, bh, bm, bl);
      acc = mm16(af, bh, acc); acc = mm16(af, bm, acc); acc = mm16(af, bl, acc);
    }
    if (j15 < 8) {
#pragma unroll
      for (int r = 0; r < 4; ++r) {
        int n = mt * 16 + (l >> 4) * 4 + r;
        gsm[(br * 64 + n) * 8 + j15] = acc[r] * rinv2_s[br][n];
      }
    }
  }
  __syncthreads();

  // ---------------- B6: f = g @ gw2 + gb2 (vector, gw2 from L2) ----------------
  {
    int n0 = tid >> 5, hq = tid & 31;
    float4 wreg[8];
#pragma unroll
    for (int j = 0; j < 8; ++j) wreg[j] = ((const float4*)gw2)[j * 32 + hq];
    float4 bquad = ((const float4*)gb2s)[hq];
#pragma unroll
    for (int br = 0; br < 3; ++br) {
      float4* f4b = (br == 0) ? fq4 : (br == 1) ? fk4 : fv4;
#pragma unroll
      for (int half = 0; half < 2; ++half) {
        int n = n0 + 32 * half;
        const float* g = gsm + (br * 64 + n) * 8;
        float4 g0 = *(const float4*)g;
        float4 g1 = *(const float4*)(g + 4);
        float4 a = bquad;
        fma4(a, g0.x, wreg[0]); fma4(a, g0.y, wreg[1]); fma4(a, g0.z, wreg[2]); fma4(a, g0.w, wreg[3]);
        fma4(a, g1.x, wreg[4]); fma4(a, g1.y, wreg[5]); fma4(a, g1.z, wreg[6]); fma4(a, g1.w, wreg[7]);
        f4b[n * FSQ + hq] = a;
      }
    }
  }
  __syncthreads();

  // ---------------- C0: kT build + idx u16 staging (into dead gw1T) ----------------
  float* kT = U;             // 128*68
  float* Pp = U + 8704;      // [2][25][64]
  unsigned short* idxp = (unsigned short*)gw1T;  // [128][32] u16
  {
    const int c = tid >> 6;
    const int n = tid & 63;
    float4 v0 = fk4[n * FSQ + 2 * c];
    float4 v1 = fk4[n * FSQ + 2 * c + 1];
    const float* p0 = (const float*)&v0;
    const float* p1 = (const float*)&v1;
#pragma unroll
    for (int e = 0; e < 4; ++e) kT[(8 * c + e) * AS + n] = p0[e];
#pragma unroll
    for (int e = 0; e < 4; ++e) kT[(8 * c + 4 + e) * AS + n] = p1[e];
    for (int i = tid; i < 3200; i += T) {
      int lr = i / 25, s = i - lr * 25;
      idxp[lr * 32 + s] = (unsigned short)idxg[i];
    }
  }
  __syncthreads();

  // ---------------- C1: qk_sample b64, exact sequential-l order (waves 0-1)
  //                      || cumsum all rows (waves 2-3) ----------------
  const float gamma = *gammap;
  if (tid < 128) {
    const int w = wid;            // P half: l-range w*64 .. w*64+63, sequential
    const int na = l & 31;        // n pair (2na, 2na+1)
    const int sh = l >> 5;        // s subrange: 0..12 | 13..24
    const int s0 = sh ? 13 : 0;
    const int scnt = sh ? 12 : 13;
    float acc0[13], acc1[13];
#pragma unroll
    for (int si = 0; si < 13; ++si) { acc0[si] = 0.f; acc1[si] = 0.f; }
    const float* q0 = fq + (2 * na) * FS + w * 64;
    const float* q1 = q0 + FS;
    for (int lb = 0; lb < 16; ++lb) {
      float4 qa = *(const float4*)(q0 + 4 * lb);
      float4 qb = *(const float4*)(q1 + 4 * lb);
      const float qs0[4] = {qa.x, qa.y, qa.z, qa.w};
      const float qs1[4] = {qb.x, qb.y, qb.z, qb.w};
#pragma unroll
      for (int i = 0; i < 4; ++i) {
        const int lrow = w * 64 + 4 * lb + i;   // wave-uniform
        u32x4 i0 = *(const u32x4*)(idxp + lrow * 32);
        u32x4 i1 = *(const u32x4*)(idxp + lrow * 32 + 8);
        u32x4 i2 = *(const u32x4*)(idxp + lrow * 32 + 16);
        unsigned i3 = *(const unsigned*)(idxp + lrow * 32 + 24);
        unsigned iw[13] = {i0.x, i0.y, i0.z, i0.w, i1.x, i1.y, i1.z, i1.w,
                           i2.x, i2.y, i2.z, i2.w, i3};
        const float qv0 = qs0[i], qv1 = qs1[i];
#pragma unroll
        for (int si = 0; si < 13; ++si) {
          if (si < scnt) {
            int s = s0 + si;
            unsigned ki = (iw[s >> 1] >> ((s & 1) * 16)) & 0xFFFFu;
            float2 kv = *(const float2*)(kT + ki * AS + 2 * na);
            acc0[si] = fmaf(qv0, kv.x, acc0[si]);
            acc1[si] = fmaf(qv1, kv.y, acc1[si]);
          }
        }
      }
    }
#pragma unroll
    for (int si = 0; si < 13; ++si) {
      if (si < scnt) {
        int s = s0 + si;
        float2 pr; pr.x = acc0[si]; pr.y = acc1[si];
        *(float2*)(Pp + (w * 25 + s) * 64 + 2 * na) = pr;
      }
    }
  } else if (tid < 256) {
    const int h = tid - 128;
    float acc = 0.f;
    for (int n = 0; n < 64; ++n) {
      acc += fv[n * FS + h];
      outb[n * 128 + h] = fmaf(gamma, acc, xb[n * 128 + h]);
    }
  }
  __syncthreads();

  // ---------------- C2: M + top-25 (wave 0) || vT build (waves 2-15) ----------------
  float* vT = U;             // 128*68 (kT dead)
  if (tid < 64) {
    if (tid >= 25 && tid < 32) mte[tid] = 0;
    const float* P0 = Pp;
    const float* P1 = Pp + 1600;
    float mx = -INFINITY, su = 0.f;
#pragma unroll
    for (int s = 0; s < 25; ++s) {
      float vsum = P0[s * 64 + tid] + P1[s * 64 + tid];
      mx = fmaxf(mx, vsum);
      su += vsum;
    }
    float v = mx - su * (1.0f / 128.0f);
    for (int it = 0; it < 25; ++it) {
      float bv2 = v;
      int bi = tid;
#pragma unroll
      for (int off = 32; off > 0; off >>= 1) {
        float ov = __shfl_xor(bv2, off);
        int oi = __shfl_xor(bi, off);
        if (ov > bv2 || (ov == bv2 && oi < bi)) { bv2 = ov; bi = oi; }
      }
      if (tid == 0) mte[it] = bi;
      if (tid == bi) v = -INFINITY;
    }
  } else if (tid >= 128) {
    for (int i = tid - 128; i < 8192; i += 896) {
      int h2 = i >> 6, n = i & 63;
      vT[h2 * AS + n] = fv[n * FS + h2];
    }
  }
  __syncthreads();

  // ---------------- C3: dense scores MFMA (waves 0-1, RNE split2) ----------------
  float* sc = U + 8704;      // 25*68 (Pp dead)
  if (tid < 128) {
    const int wsc = wid;
    const int lr = l & 31;
    const int kg = (l >> 5) * 4;
    const int qr = mte[lr];
    const float scale = 0.08838834764831845f;
    f32x16 acc = (f32x16)0.f;
    for (int ks = 0; ks < 8; ++ks) {
      int kb = ks * 16;
      float4 a0 = *(const float4*)(fq + qr * FS + kb + kg);
      float4 a1 = *(const float4*)(fq + qr * FS + kb + 8 + kg);
      float4 b0 = *(const float4*)(fk + (wsc * 32 + lr) * FS + kb + kg);
      float4 b1 = *(const float4*)(fk + (wsc * 32 + lr) * FS + kb + 8 + kg);
      short8 ah, al2, bh, bl;
      split2(a0, a1, ah, al2);
      split2(b0, b1, bh, bl);
      acc = mm32(ah, bh, acc);
      acc = mm32(ah, bl, acc);
      acc = mm32(al2, bh, acc);
    }
#pragma unroll
    for (int reg = 0; reg < 16; ++reg) {
      int uu = (reg & 3) + 8 * (reg >> 2) + 4 * (l >> 5);
      if (uu < 25) sc[uu * AS + wsc * 32 + lr] = acc[reg] * scale;
    }
  }
  __syncthreads();

  // ---------------- C4: softmax over n (16 lanes per selected row) ----------------
  if (tid < 400) {
    int u = tid >> 4, g = tid & 15;
    float4* s4 = (float4*)(sc + u * AS);
    float4 v = s4[g];
    float mx = fmaxf(fmaxf(v.x, v.y), fmaxf(v.z, v.w));
    for (int off = 8; off; off >>= 1) mx = fmaxf(mx, __shfl_xor(mx, off));
    float4 e;
    e.x = __expf(v.x - mx); e.y = __expf(v.y - mx);
    e.z = __expf(v.z - mx); e.w = __expf(v.w - mx);
    float su = e.x + e.y + e.z + e.w;
    for (int off = 8; off; off >>= 1) su += __shfl_xor(su, off);
    float inv = 1.0f / su;
    e.x *= inv; e.y *= inv; e.z *= inv; e.w *= inv;
    s4[g] = e;
  }
  __syncthreads();

  // ---------------- C5: upd MFMA: out[mte[u]] = gamma*(attn@v) + x ----------------
  if (tid < 512) {
    const int w8 = wid;
    const int li = l & 15;
    const int kg4 = (l >> 4) * 4;
#pragma unroll
    for (int i = 0; i < 2; ++i) {
      int t = w8 * 2 + i;
      int ut = t >> 3, ht = t & 7;
      int u = ut * 16 + li;
      f32x4 acc = (f32x4)0.f;
#pragma unroll
      for (int ks = 0; ks < 2; ++ks) {
        int kb = ks * 32;
        float4 a0 = *(const float4*)(sc + u * AS + kb + kg4);
        float4 a1 = *(const float4*)(sc + u * AS + kb + 16 + kg4);
        float4 b0 = *(const float4*)(vT + (ht * 16 + li) * AS + kb + kg4);
        float4 b1 = *(const float4*)(vT + (ht * 16 + li) * AS + kb + 16 + kg4);
        short8 ah, al2, bh, bl;
        split2(a0, a1, ah, al2);
        split2(b0, b1, bh, bl);
        acc = mm16(ah, bh, acc);
        acc = mm16(ah, bl, acc);
        acc = mm16(al2, bh, acc);
      }
      int hcol = ht * 16 + li;
#pragma unroll
      for (int r = 0; r < 4; ++r) {
        int uu = ut * 16 + (l >> 4) * 4 + r;
        if (uu < 25) {
          int row = mte[uu];
          int o = row * 128 + hcol;
          outb[o] = fmaf(gamma, acc[r], xb[o]);
        }
      }
    }
  }
}

extern "C" void kernel_launch(void* const* d_in, const int* in_sizes, int n_in,
                              void* d_out, int out_size, void* d_ws, size_t ws_size,
                              hipStream_t stream) {
  const float* x   = (const float*)d_in[0];
  const float* wq  = (const float*)d_in[1];
  const float* bq  = (const float*)d_in[2];
  const float* wk  = (const float*)d_in[3];
  const float* bk  = (const float*)d_in[4];
  const float* wv  = (const float*)d_in[5];
  const float* bv  = (const float*)d_in[6];
  const float* gw1 = (const float*)d_in[7];
  const float* gb1 = (const float*)d_in[8];
  const float* gw2 = (const float*)d_in[9];
  const float* gb2 = (const float*)d_in[10];
  const float* gm  = (const float*)d_in[11];
  const int* idx   = (const int*)d_in[12];
  float* out = (float*)d_out;
  int B = in_sizes[0] / (64 * 128);
  hipLaunchKernelGGL(gcn_ssa_kernel, dim3(B), dim3(T), 0, stream,
                     x, wq, bq, wk, bk, wv, bv, gw1, gb1, gw2, gb2, gm, idx, out);
}

// Round 11
// 286.657 us; speedup vs baseline: 1.9853x; 1.9853x over previous
//
#include <hip/hip_runtime.h>
#include <math.h>

#define T 1024
#define FS 132   // feature row stride (floats)
#define FSQ 33   // in float4
#define AS 68    // scratch row stride

typedef __attribute__((ext_vector_type(8)))  short short8;
typedef __attribute__((ext_vector_type(4)))  float f32x4;
typedef __attribute__((ext_vector_type(16))) float f32x16;
typedef __attribute__((ext_vector_type(4)))  unsigned u32x4;
typedef __attribute__((ext_vector_type(2)))  unsigned u32x2;

__device__ __forceinline__ void fma4(float4& a, float s, const float4 b) {
  a.x = fmaf(s, b.x, a.x);
  a.y = fmaf(s, b.y, a.y);
  a.z = fmaf(s, b.z, a.z);
  a.w = fmaf(s, b.w, a.w);
}
__device__ __forceinline__ unsigned bf16rne(float f) {
  unsigned u = __float_as_uint(f);
  return (u + 0x7FFFu + ((u >> 16) & 1u)) >> 16;
}
// RNE 3-way split (R7/R8/R10-validated): x ~= h + m + l, error class ~2^-26
__device__ __forceinline__ void split3(float4 a, float4 b, short8& vh, short8& vm, short8& vl) {
  const float xs[8] = {a.x, a.y, a.z, a.w, b.x, b.y, b.z, b.w};
#pragma unroll
  for (int e = 0; e < 8; ++e) {
    float x = xs[e];
    unsigned h = bf16rne(x);
    float r1 = x - __uint_as_float(h << 16);
    unsigned m = bf16rne(r1);
    float r2 = r1 - __uint_as_float(m << 16);
    unsigned l2 = bf16rne(r2);
    vh[e] = (short)h; vm[e] = (short)m; vl[e] = (short)l2;
  }
}
__device__ __forceinline__ void split2(float4 a, float4 b, short8& vh, short8& vl) {
  const float xs[8] = {a.x, a.y, a.z, a.w, b.x, b.y, b.z, b.w};
#pragma unroll
  for (int e = 0; e < 8; ++e) {
    float x = xs[e];
    unsigned h = bf16rne(x);
    float r1 = x - __uint_as_float(h << 16);
    unsigned l2 = bf16rne(r1);
    vh[e] = (short)h; vl[e] = (short)l2;
  }
}
__device__ __forceinline__ f32x16 mm32(short8 a, short8 b, f32x16 c) {
  return __builtin_amdgcn_mfma_f32_32x32x16_bf16(a, b, c, 0, 0, 0);
}
__device__ __forceinline__ f32x4 mm16(short8 a, short8 b, f32x4 c) {
  return __builtin_amdgcn_mfma_f32_16x16x32_bf16(a, b, c, 0, 0, 0);
}

__global__ __launch_bounds__(T) void gcn_ssa_kernel(
    const float* __restrict__ x,
    const float* __restrict__ wq, const float* __restrict__ bq,
    const float* __restrict__ wk, const float* __restrict__ bk,
    const float* __restrict__ wv, const float* __restrict__ bv,
    const float* __restrict__ gw1, const float* __restrict__ gb1,
    const float* __restrict__ gw2, const float* __restrict__ gb2,
    const float* __restrict__ gammap, const int* __restrict__ idxg,
    float* __restrict__ out)
{
  const int b = blockIdx.x, tid = threadIdx.x;
  const int l = tid & 63;
  const int wid = tid >> 6;
  const float* xb = x + (size_t)b * 8192;
  float* outb = out + (size_t)b * 8192;

  __shared__ __align__(16) float fq[64 * FS];
  __shared__ __align__(16) float fk[64 * FS];
  __shared__ __align__(16) float fv[64 * FS];
  __shared__ __align__(16) float U[11904];      // xT+bias | adjB/t1T/hT/gsm | kT/Pp/sc/vT
  __shared__ __align__(16) float gw1T[16 * FS]; // rows 8-15 zero
  __shared__ __align__(16) float gb1s[8];
  __shared__ __align__(16) float gb2s[128];
  __shared__ float rinv_s[3][64], nrm_s[3][64], rinv2_s[3][64];
  __shared__ int mte[32];

  float4* fq4 = (float4*)fq;
  float4* fk4 = (float4*)fk;
  float4* fv4 = (float4*)fv;

  // ---------------- A0: stage xT (stride 68), biases, gw1T ----------------
  {
    const float4* xg = (const float4*)xb;
    for (int i = tid; i < 2048; i += T) {
      int c = i & 63, hq = i >> 6;
      float4 v = xg[c * 32 + hq];
      int h = hq * 4;
      U[(h + 0) * AS + c] = v.x;
      U[(h + 1) * AS + c] = v.y;
      U[(h + 2) * AS + c] = v.z;
      U[(h + 3) * AS + c] = v.w;
    }
    if (tid < 192) U[8704 + tid] = (tid < 64) ? bq[tid] : (tid < 128) ? bk[tid - 64] : bv[tid - 128];
    for (int i = tid; i < 2048; i += T) {
      int j = i >> 7, h = i & 127;
      gw1T[j * FS + h] = (j < 8) ? gw1[h * 8 + j] : 0.f;
    }
    if (tid < 8) gb1s[tid] = gb1[tid];
    if (tid < 128) gb2s[tid] = gb2[tid];
  }
  __syncthreads();

  // ---------------- A1: 3 projections via MFMA 6-term (12 waves, RNE split) ----------------
  if (wid < 12) {
    const int p = wid >> 2, strip = wid & 3;
    const float* wsel = (p == 0) ? wq : (p == 1) ? wk : wv;
    float* fdst = (p == 0) ? fq : (p == 1) ? fk : fv;
    const int lr = l & 31, kg = (l >> 5) * 4;
    const int h = strip * 32 + lr;
    f32x16 acc0 = (f32x16)0.f, acc1 = (f32x16)0.f;
    for (int ks = 0; ks < 4; ++ks) {
      int kb = ks * 16;
      float4 b0 = *(const float4*)(U + h * AS + kb + kg);
      float4 b1 = *(const float4*)(U + h * AS + kb + 8 + kg);
      short8 bh, bm, bl;
      split3(b0, b1, bh, bm, bl);
      float4 a0 = *(const float4*)(wsel + lr * 64 + kb + kg);
      float4 a1 = *(const float4*)(wsel + lr * 64 + kb + 8 + kg);
      short8 ah, am, al;
      split3(a0, a1, ah, am, al);
      acc0 = mm32(ah, bh, acc0); acc0 = mm32(ah, bm, acc0); acc0 = mm32(am, bh, acc0);
      acc0 = mm32(ah, bl, acc0); acc0 = mm32(al, bh, acc0); acc0 = mm32(am, bm, acc0);
      a0 = *(const float4*)(wsel + (32 + lr) * 64 + kb + kg);
      a1 = *(const float4*)(wsel + (32 + lr) * 64 + kb + 8 + kg);
      split3(a0, a1, ah, am, al);
      acc1 = mm32(ah, bh, acc1); acc1 = mm32(ah, bm, acc1); acc1 = mm32(am, bh, acc1);
      acc1 = mm32(ah, bl, acc1); acc1 = mm32(al, bh, acc1); acc1 = mm32(am, bm, acc1);
    }
#pragma unroll
    for (int reg = 0; reg < 16; ++reg) {
      int ro = (reg & 3) + 8 * (reg >> 2) + 4 * (l >> 5);
      fdst[ro * FS + h] = acc0[reg] + U[8704 + p * 64 + ro];
      fdst[(32 + ro) * FS + h] = acc1[reg] + U[8704 + p * 64 + 32 + ro];
    }
  }
  __syncthreads();

  // ---------------- B1: row stats, all 3 branches ----------------
  {
    int row = tid >> 4, g = tid & 15;
#pragma unroll
    for (int br = 0; br < 3; ++br) {
      const float4* f4b = (br == 0) ? fq4 : (br == 1) ? fk4 : fv4;
      float4 aa = f4b[row * FSQ + 2 * g];
      float4 cc = f4b[row * FSQ + 2 * g + 1];
      float s0 = aa.x + aa.y + aa.z + aa.w + cc.x + cc.y + cc.z + cc.w;
      float s1 = aa.x * aa.x + aa.y * aa.y + aa.z * aa.z + aa.w * aa.w +
                 cc.x * cc.x + cc.y * cc.y + cc.z * cc.z + cc.w * cc.w;
      for (int off = 8; off; off >>= 1) {
        s0 += __shfl_xor(s0, off);
        s1 += __shfl_xor(s1, off);
      }
      if (g == 0) {
        rinv_s[br][row] = (s0 == 0.0f) ? 0.0f : (1.0f / s0);
        nrm_s[br][row] = 1.0f / fmaxf(sqrtf(s1), 1e-8f);
      }
    }
  }
  __syncthreads();

  unsigned short* adjw = (unsigned short*)U;   // [3][64][72] bf16 exact
  float* t1T = U + 6912;                       // [3*8][68]
  float* hT  = U + 8544;                       // [3*8][68]
  float* gsm = U + 10176;                      // [3*64][8]

  // ---------------- B2: symmetric grams (9 waves) || t1 MFMA (7 waves) — RNE ----------------
  if (wid < 9) {
    const int br = wid / 3, t3 = wid % 3;
    const float* f = (br == 0) ? fq : (br == 1) ? fk : fv;
    const int lr = l & 31, kg = (l >> 5) * 4;
    f32x16 acc = (f32x16)0.f;
    if (t3 < 2) {
      // diagonal tile: A fragment == B fragment (one split per K-step)
      const int r0 = t3 * 32;
      for (int ks = 0; ks < 8; ++ks) {
        int kb = ks * 16;
        float4 a0 = *(const float4*)(f + (r0 + lr) * FS + kb + kg);
        float4 a1 = *(const float4*)(f + (r0 + lr) * FS + kb + 8 + kg);
        short8 h, m, lo;
        split3(a0, a1, h, m, lo);
        acc = mm32(h, h, acc); acc = mm32(h, m, acc); acc = mm32(m, h, acc);
        acc = mm32(h, lo, acc); acc = mm32(lo, h, acc); acc = mm32(m, m, acc);
      }
      float nm = nrm_s[br][r0 + lr];
#pragma unroll
      for (int reg = 0; reg < 16; ++reg) {
        int rowg = r0 + (reg & 3) + 8 * (reg >> 2) + 4 * (l >> 5);
        int m = r0 + lr;
        float sim = acc[reg] * nrm_s[br][rowg] * nm;
        unsigned short e = (sim > 0.5f) ? (unsigned short)0x3F80 : (unsigned short)0;
        if (rowg == m) e = (sim > 0.5f) ? (unsigned short)0x4000 : (unsigned short)0x3F80;
        adjw[(br * 64 + rowg) * 72 + m] = e;
      }
    } else {
      // off-diagonal rows 0-31 x cols 32-63, mirrored (gram exactly symmetric)
      for (int ks = 0; ks < 8; ++ks) {
        int kb = ks * 16;
        float4 a0 = *(const float4*)(f + lr * FS + kb + kg);
        float4 a1 = *(const float4*)(f + lr * FS + kb + 8 + kg);
        float4 b0 = *(const float4*)(f + (32 + lr) * FS + kb + kg);
        float4 b1 = *(const float4*)(f + (32 + lr) * FS + kb + 8 + kg);
        short8 ah, am, al, bh, bm, bl;
        split3(a0, a1, ah, am, al);
        split3(b0, b1, bh, bm, bl);
        acc = mm32(ah, bh, acc); acc = mm32(ah, bm, acc); acc = mm32(am, bh, acc);
        acc = mm32(ah, bl, acc); acc = mm32(al, bh, acc); acc = mm32(am, bm, acc);
      }
      float nm = nrm_s[br][32 + lr];
#pragma unroll
      for (int reg = 0; reg < 16; ++reg) {
        int rowg = (reg & 3) + 8 * (reg >> 2) + 4 * (l >> 5);
        int m = 32 + lr;
        float sim = acc[reg] * nrm_s[br][rowg] * nm;
        unsigned short e = (sim > 0.5f) ? (unsigned short)0x3F80 : (unsigned short)0;
        adjw[(br * 64 + rowg) * 72 + m] = e;
        adjw[(br * 64 + m) * 72 + rowg] = e;
      }
    }
  } else {
    // t1: 12 tiles over 7 waves (RNE split)
    const int j15 = l & 15, kg4 = (l >> 4) * 4;
    short8 gbh[4], gbm[4], gbl[4];
#pragma unroll
    for (int ks = 0; ks < 4; ++ks) {
      int kb = ks * 32;
      float4 b0 = *(const float4*)(gw1T + j15 * FS + kb + kg4);
      float4 b1 = *(const float4*)(gw1T + j15 * FS + kb + 16 + kg4);
      split3(b0, b1, gbh[ks], gbm[ks], gbl[ks]);
    }
#pragma unroll
    for (int rep = 0; rep < 2; ++rep) {
      int t = (wid - 9) + rep * 7;
      if (t < 12) {
        int br = t >> 2, mt = t & 3;
        const float* f = (br == 0) ? fq : (br == 1) ? fk : fv;
        f32x4 acc = (f32x4)0.f;
        for (int ks = 0; ks < 4; ++ks) {
          int kb = ks * 32;
          float4 a0 = *(const float4*)(f + (mt * 16 + j15) * FS + kb + kg4);
          float4 a1 = *(const float4*)(f + (mt * 16 + j15) * FS + kb + 16 + kg4);
          short8 ah, am, al;
          split3(a0, a1, ah, am, al);
          acc = mm16(ah, gbh[ks], acc); acc = mm16(ah, gbm[ks], acc); acc = mm16(am, gbh[ks], acc);
          acc = mm16(ah, gbl[ks], acc); acc = mm16(al, gbh[ks], acc); acc = mm16(am, gbm[ks], acc);
        }
        if (j15 < 8) {
#pragma unroll
          for (int r = 0; r < 4; ++r) {
            int n = mt * 16 + (l >> 4) * 4 + r;
            t1T[(br * 8 + j15) * AS + n] = acc[r] * rinv_s[br][n];
          }
        }
      }
    }
  }
  __syncthreads();

  // ---------------- B4: in-wave adj row sums + h = relu(rinv2*(adj@t1)+gb1) ----------------
  if (tid < 768) {
    const int br = wid >> 2, mt = wid & 3;
    const int j15 = l & 15, kg4 = (l >> 4) * 4;
    float rinv2;
    {
      const unsigned short* rp = adjw + (br * 64 + mt * 16 + j15) * 72 + (l >> 4) * 16;
      u32x4 v0 = *(const u32x4*)rp;
      u32x4 v1 = *(const u32x4*)(rp + 8);
      unsigned wds[8] = {v0.x, v0.y, v0.z, v0.w, v1.x, v1.y, v1.z, v1.w};
      float s = 0.f;
#pragma unroll
      for (int e = 0; e < 8; ++e) {
        s += __uint_as_float(wds[e] << 16);
        s += __uint_as_float(wds[e] & 0xFFFF0000u);
      }
      s += __shfl_xor(s, 16);
      s += __shfl_xor(s, 32);
      rinv2 = 1.0f / s;
      if (l < 16) rinv2_s[br][mt * 16 + l] = rinv2;  // for B5
    }
    // shuffles hoisted OUT of divergent region (all 64 lanes active)
    float rv4[4];
#pragma unroll
    for (int r = 0; r < 4; ++r) rv4[r] = __shfl(rinv2, (l >> 4) * 4 + r);

    const int arow = br * 64 + mt * 16 + j15;
    f32x4 acc = (f32x4)0.f;
#pragma unroll
    for (int ks = 0; ks < 2; ++ks) {
      int kb = ks * 32;
      u32x2 lo = *(const u32x2*)(adjw + arow * 72 + kb + kg4);
      u32x2 hi = *(const u32x2*)(adjw + arow * 72 + kb + 16 + kg4);
      u32x4 cc; cc.x = lo.x; cc.y = lo.y; cc.z = hi.x; cc.w = hi.y;
      short8 af = __builtin_bit_cast(short8, cc);
      float4 b0 = *(const float4*)(t1T + (br * 8 + j15) * AS + kb + kg4);
      float4 b1 = *(const float4*)(t1T + (br * 8 + j15) * AS + kb + 16 + kg4);
      short8 bh, bm, bl;
      split3(b0, b1, bh, bm, bl);
      acc = mm16(af, bh, acc); acc = mm16(af, bm, acc); acc = mm16(af, bl, acc);
    }
    if (j15 < 8) {
      float g1 = gb1s[j15];
#pragma unroll
      for (int r = 0; r < 4; ++r) {
        int n = mt * 16 + (l >> 4) * 4 + r;
        hT[(br * 8 + j15) * AS + n] = fmaxf(fmaf(acc[r], rv4[r], g1), 0.0f);
      }
    }
  }
  __syncthreads();

  // ---------------- B5: g = rinv2*(adj@h) ----------------
  if (tid < 768) {
    const int br = wid >> 2, mt = wid & 3;
    const int j15 = l & 15, kg4 = (l >> 4) * 4;
    const int arow = br * 64 + mt * 16 + j15;
    f32x4 acc = (f32x4)0.f;
#pragma unroll
    for (int ks = 0; ks < 2; ++ks) {
      int kb = ks * 32;
      u32x2 lo = *(const u32x2*)(adjw + arow * 72 + kb + kg4);
      u32x2 hi = *(const u32x2*)(adjw + arow * 72 + kb + 16 + kg4);
      u32x4 cc; cc.x = lo.x; cc.y = lo.y; cc.z = hi.x; cc.w = hi.y;
      short8 af = __builtin_bit_cast(short8, cc);
      float4 b0 = *(const float4*)(hT + (br * 8 + j15) * AS + kb + kg4);
      float4 b1 = *(const float4*)(hT + (br * 8 + j15) * AS + kb + 16 + kg4);
      short8 bh, bm, bl;
      split3(b0, b1, bh, bm, bl);
      acc = mm16(af, bh, acc); acc = mm16(af, bm, acc); acc = mm16(af, bl, acc);
    }
    if (j15 < 8) {
#pragma unroll
      for (int r = 0; r < 4; ++r) {
        int n = mt * 16 + (l >> 4) * 4 + r;
        gsm[(br * 64 + n) * 8 + j15] = acc[r] * rinv2_s[br][n];
      }
    }
  }
  __syncthreads();

  // ---------------- B6: f = g @ gw2 + gb2 (vector, gw2 from L2) ----------------
  {
    int n0 = tid >> 5, hq = tid & 31;
    float4 wreg[8];
#pragma unroll
    for (int j = 0; j < 8; ++j) wreg[j] = ((const float4*)gw2)[j * 32 + hq];
    float4 bquad = ((const float4*)gb2s)[hq];
#pragma unroll
    for (int br = 0; br < 3; ++br) {
      float4* f4b = (br == 0) ? fq4 : (br == 1) ? fk4 : fv4;
#pragma unroll
      for (int half = 0; half < 2; ++half) {
        int n = n0 + 32 * half;
        const float* g = gsm + (br * 64 + n) * 8;
        float4 g0 = *(const float4*)g;
        float4 g1 = *(const float4*)(g + 4);
        float4 a = bquad;
        fma4(a, g0.x, wreg[0]); fma4(a, g0.y, wreg[1]); fma4(a, g0.z, wreg[2]); fma4(a, g0.w, wreg[3]);
        fma4(a, g1.x, wreg[4]); fma4(a, g1.y, wreg[5]); fma4(a, g1.z, wreg[6]); fma4(a, g1.w, wreg[7]);
        f4b[n * FSQ + hq] = a;
      }
    }
  }
  __syncthreads();

  // ---------------- C0: kT build (R8 verbatim; no idx staging) ----------------
  float* kT = U;             // 128*68
  float* Pp = U + 8704;      // [2][25][64]
  {
    const int c = tid >> 6;
    const int n = tid & 63;
    float4 v0 = fk4[n * FSQ + 2 * c];
    float4 v1 = fk4[n * FSQ + 2 * c + 1];
    const float* p0 = (const float*)&v0;
    const float* p1 = (const float*)&v1;
#pragma unroll
    for (int e = 0; e < 4; ++e) kT[(8 * c + e) * AS + n] = p0[e];
#pragma unroll
    for (int e = 0; e < 4; ++e) kT[(8 * c + 4 + e) * AS + n] = p1[e];
  }
  __syncthreads();

  // ---------------- C1: qk_sample (R8 verbatim: SGPR idx s_loads, static acc[25])
  //                      || cumsum all rows (waves 2-3) ----------------
  const float gamma = *gammap;
  if (tid < 128) {
    const int w = wid, n = l;
    float acc[25];
#pragma unroll
    for (int s = 0; s < 25; ++s) acc[s] = 0.f;
    const float* qrow = fq + n * FS + w * 64;
    for (int lb = 0; lb < 16; ++lb) {
      float4 qv = *(const float4*)(qrow + 4 * lb);
      const float* qp = (const float*)&qv;
#pragma unroll
      for (int i = 0; i < 4; ++i) {
        const float qs = qp[i];
        const int base = __builtin_amdgcn_readfirstlane((w * 64 + 4 * lb + i) * 25);
#pragma unroll
        for (int s = 0; s < 25; ++s) {
          acc[s] = fmaf(qs, kT[idxg[base + s] * AS + n], acc[s]);
        }
      }
    }
    float* P = Pp + w * 1600;
#pragma unroll
    for (int s = 0; s < 25; ++s) P[s * 64 + n] = acc[s];
  } else if (tid < 256) {
    const int h = tid - 128;
    float acc = 0.f;
    for (int n = 0; n < 64; ++n) {
      acc += fv[n * FS + h];
      outb[n * 128 + h] = fmaf(gamma, acc, xb[n * 128 + h]);
    }
  }
  __syncthreads();

  // ---------------- C2: M + top-25 (wave 0) || vT build (waves 2-15) ----------------
  float* vT = U;             // 128*68 (kT dead)
  if (tid < 64) {
    if (tid >= 25 && tid < 32) mte[tid] = 0;
    const float* P0 = Pp;
    const float* P1 = Pp + 1600;
    float mx = -INFINITY, su = 0.f;
#pragma unroll
    for (int s = 0; s < 25; ++s) {
      float vsum = P0[s * 64 + tid] + P1[s * 64 + tid];
      mx = fmaxf(mx, vsum);
      su += vsum;
    }
    float v = mx - su * (1.0f / 128.0f);
    for (int it = 0; it < 25; ++it) {
      float bv2 = v;
      int bi = tid;
#pragma unroll
      for (int off = 32; off > 0; off >>= 1) {
        float ov = __shfl_xor(bv2, off);
        int oi = __shfl_xor(bi, off);
        if (ov > bv2 || (ov == bv2 && oi < bi)) { bv2 = ov; bi = oi; }
      }
      if (tid == 0) mte[it] = bi;
      if (tid == bi) v = -INFINITY;
    }
  } else if (tid >= 128) {
    for (int i = tid - 128; i < 8192; i += 896) {
      int h2 = i >> 6, n = i & 63;
      vT[h2 * AS + n] = fv[n * FS + h2];
    }
  }
  __syncthreads();

  // ---------------- C3: dense scores MFMA (waves 0-1, RNE split2) ----------------
  float* sc = U + 8704;      // 25*68 (Pp dead)
  if (tid < 128) {
    const int wsc = wid;
    const int lr = l & 31;
    const int kg = (l >> 5) * 4;
    const int qr = mte[lr];
    const float scale = 0.08838834764831845f;
    f32x16 acc = (f32x16)0.f;
    for (int ks = 0; ks < 8; ++ks) {
      int kb = ks * 16;
      float4 a0 = *(const float4*)(fq + qr * FS + kb + kg);
      float4 a1 = *(const float4*)(fq + qr * FS + kb + 8 + kg);
      float4 b0 = *(const float4*)(fk + (wsc * 32 + lr) * FS + kb + kg);
      float4 b1 = *(const float4*)(fk + (wsc * 32 + lr) * FS + kb + 8 + kg);
      short8 ah, al2, bh, bl;
      split2(a0, a1, ah, al2);
      split2(b0, b1, bh, bl);
      acc = mm32(ah, bh, acc);
      acc = mm32(ah, bl, acc);
      acc = mm32(al2, bh, acc);
    }
#pragma unroll
    for (int reg = 0; reg < 16; ++reg) {
      int uu = (reg & 3) + 8 * (reg >> 2) + 4 * (l >> 5);
      if (uu < 25) sc[uu * AS + wsc * 32 + lr] = acc[reg] * scale;
    }
  }
  __syncthreads();

  // ---------------- C4: softmax over n (16 lanes per selected row) ----------------
  if (tid < 400) {
    int u = tid >> 4, g = tid & 15;
    float4* s4 = (float4*)(sc + u * AS);
    float4 v = s4[g];
    float mx = fmaxf(fmaxf(v.x, v.y), fmaxf(v.z, v.w));
    for (int off = 8; off; off >>= 1) mx = fmaxf(mx, __shfl_xor(mx, off));
    float4 e;
    e.x = __expf(v.x - mx); e.y = __expf(v.y - mx);
    e.z = __expf(v.z - mx); e.w = __expf(v.w - mx);
    float su = e.x + e.y + e.z + e.w;
    for (int off = 8; off; off >>= 1) su += __shfl_xor(su, off);
    float inv = 1.0f / su;
    e.x *= inv; e.y *= inv; e.z *= inv; e.w *= inv;
    s4[g] = e;
  }
  __syncthreads();

  // ---------------- C5: upd MFMA: out[mte[u]] = gamma*(attn@v) + x ----------------
  if (tid < 512) {
    const int w8 = wid;
    const int li = l & 15;
    const int kg4 = (l >> 4) * 4;
#pragma unroll
    for (int i = 0; i < 2; ++i) {
      int t = w8 * 2 + i;
      int ut = t >> 3, ht = t & 7;
      int u = ut * 16 + li;
      f32x4 acc = (f32x4)0.f;
#pragma unroll
      for (int ks = 0; ks < 2; ++ks) {
        int kb = ks * 32;
        float4 a0 = *(const float4*)(sc + u * AS + kb + kg4);
        float4 a1 = *(const float4*)(sc + u * AS + kb + 16 + kg4);
        float4 b0 = *(const float4*)(vT + (ht * 16 + li) * AS + kb + kg4);
        float4 b1 = *(const float4*)(vT + (ht * 16 + li) * AS + kb + 16 + kg4);
        short8 ah, al2, bh, bl;
        split2(a0, a1, ah, al2);
        split2(b0, b1, bh, bl);
        acc = mm16(ah, bh, acc);
        acc = mm16(ah, bl, acc);
        acc = mm16(al2, bh, acc);
      }
      int hcol = ht * 16 + li;
#pragma unroll
      for (int r = 0; r < 4; ++r) {
        int uu = ut * 16 + (l >> 4) * 4 + r;
        if (uu < 25) {
          int row = mte[uu];
          int o = row * 128 + hcol;
          outb[o] = fmaf(gamma, acc[r], xb[o]);
        }
      }
    }
  }
}

extern "C" void kernel_launch(void* const* d_in, const int* in_sizes, int n_in,
                              void* d_out, int out_size, void* d_ws, size_t ws_size,
                              hipStream_t stream) {
  const float* x   = (const float*)d_in[0];
  const float* wq  = (const float*)d_in[1];
  const float* bq  = (const float*)d_in[2];
  const float* wk  = (const float*)d_in[3];
  const float* bk  = (const float*)d_in[4];
  const float* wv  = (const float*)d_in[5];
  const float* bv  = (const float*)d_in[6];
  const float* gw1 = (const float*)d_in[7];
  const float* gb1 = (const float*)d_in[8];
  const float* gw2 = (const float*)d_in[9];
  const float* gb2 = (const float*)d_in[10];
  const float* gm  = (const float*)d_in[11];
  const int* idx   = (const int*)d_in[12];
  float* out = (float*)d_out;
  int B = in_sizes[0] / (64 * 128);
  hipLaunchKernelGGL(gcn_ssa_kernel, dim3(B), dim3(T), 0, stream,
                     x, wq, bq, wk, bk, wv, bv, gw1, gb1, gw2, gb2, gm, idx, out);
}

// Round 12
// 252.003 us; speedup vs baseline: 2.2583x; 1.1375x over previous
//
#include <hip/hip_runtime.h>
#include <math.h>

#define T 1024
#define FS 132   // feature row stride (floats)
#define FSQ 33   // in float4
#define AS 68    // scratch row stride

typedef __attribute__((ext_vector_type(8)))  short short8;
typedef __attribute__((ext_vector_type(4)))  float f32x4;
typedef __attribute__((ext_vector_type(16))) float f32x16;
typedef __attribute__((ext_vector_type(4)))  unsigned u32x4;
typedef __attribute__((ext_vector_type(2)))  unsigned u32x2;

__device__ __forceinline__ void fma4(float4& a, float s, const float4 b) {
  a.x = fmaf(s, b.x, a.x);
  a.y = fmaf(s, b.y, a.y);
  a.z = fmaf(s, b.z, a.z);
  a.w = fmaf(s, b.w, a.w);
}
// HW RNE converts (gfx950 native cvt; RNE == prior bit-twiddle for normal values)
__device__ __forceinline__ short bfc(float x) {
  return __builtin_bit_cast(short, (__bf16)x);
}
__device__ __forceinline__ float bff(short h) {
  return (float)__builtin_bit_cast(__bf16, h);
}
// RNE 3-way split: x ~= h + m + l, error class ~2^-26 (R7/R8/R10/R11-validated semantics)
__device__ __forceinline__ void split3(float4 a, float4 b, short8& vh, short8& vm, short8& vl) {
  const float xs[8] = {a.x, a.y, a.z, a.w, b.x, b.y, b.z, b.w};
#pragma unroll
  for (int e = 0; e < 8; ++e) {
    float x = xs[e];
    short h = bfc(x);
    float r1 = x - bff(h);
    short m = bfc(r1);
    float r2 = r1 - bff(m);
    vh[e] = h; vm[e] = m; vl[e] = bfc(r2);
  }
}
__device__ __forceinline__ void split2(float4 a, float4 b, short8& vh, short8& vl) {
  const float xs[8] = {a.x, a.y, a.z, a.w, b.x, b.y, b.z, b.w};
#pragma unroll
  for (int e = 0; e < 8; ++e) {
    float x = xs[e];
    short h = bfc(x);
    float r1 = x - bff(h);
    vh[e] = h; vl[e] = bfc(r1);
  }
}
__device__ __forceinline__ f32x16 mm32(short8 a, short8 b, f32x16 c) {
  return __builtin_amdgcn_mfma_f32_32x32x16_bf16(a, b, c, 0, 0, 0);
}
__device__ __forceinline__ f32x4 mm16(short8 a, short8 b, f32x4 c) {
  return __builtin_amdgcn_mfma_f32_16x16x32_bf16(a, b, c, 0, 0, 0);
}

__global__ __launch_bounds__(T) void gcn_ssa_kernel(
    const float* __restrict__ x,
    const float* __restrict__ wq, const float* __restrict__ bq,
    const float* __restrict__ wk, const float* __restrict__ bk,
    const float* __restrict__ wv, const float* __restrict__ bv,
    const float* __restrict__ gw1, const float* __restrict__ gb1,
    const float* __restrict__ gw2, const float* __restrict__ gb2,
    const float* __restrict__ gammap, const int* __restrict__ idxg,
    float* __restrict__ out)
{
  const int b = blockIdx.x, tid = threadIdx.x;
  const int l = tid & 63;
  const int wid = tid >> 6;
  const float* xb = x + (size_t)b * 8192;
  float* outb = out + (size_t)b * 8192;

  __shared__ __align__(16) float fq[64 * FS];
  __shared__ __align__(16) float fk[64 * FS];
  __shared__ __align__(16) float fv[64 * FS];
  __shared__ __align__(16) float U[11904];      // xT+bias | adjB/t1T/hT/gsm | kT/Pp/sc/vT
  __shared__ __align__(16) float gw1T[16 * FS]; // rows 8-15 zero
  __shared__ __align__(16) float gb1s[8];
  __shared__ __align__(16) float gb2s[128];
  __shared__ float rinv_s[3][64], nrm_s[3][64], rinv2_s[3][64];
  __shared__ int mte[32];

  float4* fq4 = (float4*)fq;
  float4* fk4 = (float4*)fk;
  float4* fv4 = (float4*)fv;

  // ---------------- A0: stage xT (stride 68), biases, gw1T ----------------
  {
    const float4* xg = (const float4*)xb;
    for (int i = tid; i < 2048; i += T) {
      int c = i & 63, hq = i >> 6;
      float4 v = xg[c * 32 + hq];
      int h = hq * 4;
      U[(h + 0) * AS + c] = v.x;
      U[(h + 1) * AS + c] = v.y;
      U[(h + 2) * AS + c] = v.z;
      U[(h + 3) * AS + c] = v.w;
    }
    if (tid < 192) U[8704 + tid] = (tid < 64) ? bq[tid] : (tid < 128) ? bk[tid - 64] : bv[tid - 128];
    for (int i = tid; i < 2048; i += T) {
      int j = i >> 7, h = i & 127;
      gw1T[j * FS + h] = (j < 8) ? gw1[h * 8 + j] : 0.f;
    }
    if (tid < 8) gb1s[tid] = gb1[tid];
    if (tid < 128) gb2s[tid] = gb2[tid];
  }
  __syncthreads();

  // ---------------- A1: 3 projections via MFMA 6-term (12 waves, RNE split) ----------------
  if (wid < 12) {
    const int p = wid >> 2, strip = wid & 3;
    const float* wsel = (p == 0) ? wq : (p == 1) ? wk : wv;
    float* fdst = (p == 0) ? fq : (p == 1) ? fk : fv;
    const int lr = l & 31, kg = (l >> 5) * 4;
    const int h = strip * 32 + lr;
    f32x16 acc0 = (f32x16)0.f, acc1 = (f32x16)0.f;
    for (int ks = 0; ks < 4; ++ks) {
      int kb = ks * 16;
      float4 b0 = *(const float4*)(U + h * AS + kb + kg);
      float4 b1 = *(const float4*)(U + h * AS + kb + 8 + kg);
      short8 bh, bm, bl;
      split3(b0, b1, bh, bm, bl);
      float4 a0 = *(const float4*)(wsel + lr * 64 + kb + kg);
      float4 a1 = *(const float4*)(wsel + lr * 64 + kb + 8 + kg);
      short8 ah, am, al;
      split3(a0, a1, ah, am, al);
      acc0 = mm32(ah, bh, acc0); acc0 = mm32(ah, bm, acc0); acc0 = mm32(am, bh, acc0);
      acc0 = mm32(ah, bl, acc0); acc0 = mm32(al, bh, acc0); acc0 = mm32(am, bm, acc0);
      a0 = *(const float4*)(wsel + (32 + lr) * 64 + kb + kg);
      a1 = *(const float4*)(wsel + (32 + lr) * 64 + kb + 8 + kg);
      split3(a0, a1, ah, am, al);
      acc1 = mm32(ah, bh, acc1); acc1 = mm32(ah, bm, acc1); acc1 = mm32(am, bh, acc1);
      acc1 = mm32(ah, bl, acc1); acc1 = mm32(al, bh, acc1); acc1 = mm32(am, bm, acc1);
    }
#pragma unroll
    for (int reg = 0; reg < 16; ++reg) {
      int ro = (reg & 3) + 8 * (reg >> 2) + 4 * (l >> 5);
      fdst[ro * FS + h] = acc0[reg] + U[8704 + p * 64 + ro];
      fdst[(32 + ro) * FS + h] = acc1[reg] + U[8704 + p * 64 + 32 + ro];
    }
  }
  __syncthreads();

  // ---------------- B1: row stats, all 3 branches ----------------
  {
    int row = tid >> 4, g = tid & 15;
#pragma unroll
    for (int br = 0; br < 3; ++br) {
      const float4* f4b = (br == 0) ? fq4 : (br == 1) ? fk4 : fv4;
      float4 aa = f4b[row * FSQ + 2 * g];
      float4 cc = f4b[row * FSQ + 2 * g + 1];
      float s0 = aa.x + aa.y + aa.z + aa.w + cc.x + cc.y + cc.z + cc.w;
      float s1 = aa.x * aa.x + aa.y * aa.y + aa.z * aa.z + aa.w * aa.w +
                 cc.x * cc.x + cc.y * cc.y + cc.z * cc.z + cc.w * cc.w;
      for (int off = 8; off; off >>= 1) {
        s0 += __shfl_xor(s0, off);
        s1 += __shfl_xor(s1, off);
      }
      if (g == 0) {
        rinv_s[br][row] = (s0 == 0.0f) ? 0.0f : (1.0f / s0);
        nrm_s[br][row] = 1.0f / fmaxf(sqrtf(s1), 1e-8f);
      }
    }
  }
  __syncthreads();

  unsigned short* adjw = (unsigned short*)U;   // [3][64][72] bf16 exact
  float* t1T = U + 6912;                       // [3*8][68]
  float* hT  = U + 8544;                       // [3*8][68]
  float* gsm = U + 10176;                      // [3*64][8]

  // ---------------- B2: symmetric grams (9 waves) || t1 MFMA (7 waves) ----------------
  if (wid < 9) {
    const int br = wid / 3, t3 = wid % 3;
    const float* f = (br == 0) ? fq : (br == 1) ? fk : fv;
    const int lr = l & 31, kg = (l >> 5) * 4;
    f32x16 acc = (f32x16)0.f;
    if (t3 < 2) {
      // diagonal tile: A fragment == B fragment (one split per K-step)
      const int r0 = t3 * 32;
      for (int ks = 0; ks < 8; ++ks) {
        int kb = ks * 16;
        float4 a0 = *(const float4*)(f + (r0 + lr) * FS + kb + kg);
        float4 a1 = *(const float4*)(f + (r0 + lr) * FS + kb + 8 + kg);
        short8 h, m, lo;
        split3(a0, a1, h, m, lo);
        acc = mm32(h, h, acc); acc = mm32(h, m, acc); acc = mm32(m, h, acc);
        acc = mm32(h, lo, acc); acc = mm32(lo, h, acc); acc = mm32(m, m, acc);
      }
      float nm = nrm_s[br][r0 + lr];
#pragma unroll
      for (int reg = 0; reg < 16; ++reg) {
        int rowg = r0 + (reg & 3) + 8 * (reg >> 2) + 4 * (l >> 5);
        int m = r0 + lr;
        float sim = acc[reg] * nrm_s[br][rowg] * nm;
        unsigned short e = (sim > 0.5f) ? (unsigned short)0x3F80 : (unsigned short)0;
        if (rowg == m) e = (sim > 0.5f) ? (unsigned short)0x4000 : (unsigned short)0x3F80;
        adjw[(br * 64 + rowg) * 72 + m] = e;
      }
    } else {
      // off-diagonal rows 0-31 x cols 32-63, mirrored (gram exactly symmetric)
      for (int ks = 0; ks < 8; ++ks) {
        int kb = ks * 16;
        float4 a0 = *(const float4*)(f + lr * FS + kb + kg);
        float4 a1 = *(const float4*)(f + lr * FS + kb + 8 + kg);
        float4 b0 = *(const float4*)(f + (32 + lr) * FS + kb + kg);
        float4 b1 = *(const float4*)(f + (32 + lr) * FS + kb + 8 + kg);
        short8 ah, am, al, bh, bm, bl;
        split3(a0, a1, ah, am, al);
        split3(b0, b1, bh, bm, bl);
        acc = mm32(ah, bh, acc); acc = mm32(ah, bm, acc); acc = mm32(am, bh, acc);
        acc = mm32(ah, bl, acc); acc = mm32(al, bh, acc); acc = mm32(am, bm, acc);
      }
      float nm = nrm_s[br][32 + lr];
#pragma unroll
      for (int reg = 0; reg < 16; ++reg) {
        int rowg = (reg & 3) + 8 * (reg >> 2) + 4 * (l >> 5);
        int m = 32 + lr;
        float sim = acc[reg] * nrm_s[br][rowg] * nm;
        unsigned short e = (sim > 0.5f) ? (unsigned short)0x3F80 : (unsigned short)0;
        adjw[(br * 64 + rowg) * 72 + m] = e;
        adjw[(br * 64 + m) * 72 + rowg] = e;
      }
    }
  } else {
    // t1: 12 tiles over 7 waves
    const int j15 = l & 15, kg4 = (l >> 4) * 4;
    short8 gbh[4], gbm[4], gbl[4];
#pragma unroll
    for (int ks = 0; ks < 4; ++ks) {
      int kb = ks * 32;
      float4 b0 = *(const float4*)(gw1T + j15 * FS + kb + kg4);
      float4 b1 = *(const float4*)(gw1T + j15 * FS + kb + 16 + kg4);
      split3(b0, b1, gbh[ks], gbm[ks], gbl[ks]);
    }
#pragma unroll
    for (int rep = 0; rep < 2; ++rep) {
      int t = (wid - 9) + rep * 7;
      if (t < 12) {
        int br = t >> 2, mt = t & 3;
        const float* f = (br == 0) ? fq : (br == 1) ? fk : fv;
        f32x4 acc = (f32x4)0.f;
        for (int ks = 0; ks < 4; ++ks) {
          int kb = ks * 32;
          float4 a0 = *(const float4*)(f + (mt * 16 + j15) * FS + kb + kg4);
          float4 a1 = *(const float4*)(f + (mt * 16 + j15) * FS + kb + 16 + kg4);
          short8 ah, am, al;
          split3(a0, a1, ah, am, al);
          acc = mm16(ah, gbh[ks], acc); acc = mm16(ah, gbm[ks], acc); acc = mm16(am, gbh[ks], acc);
          acc = mm16(ah, gbl[ks], acc); acc = mm16(al, gbh[ks], acc); acc = mm16(am, gbm[ks], acc);
        }
        if (j15 < 8) {
#pragma unroll
          for (int r = 0; r < 4; ++r) {
            int n = mt * 16 + (l >> 4) * 4 + r;
            t1T[(br * 8 + j15) * AS + n] = acc[r] * rinv_s[br][n];
          }
        }
      }
    }
  }
  __syncthreads();

  // ---------------- B4: in-wave adj row sums + h = relu(rinv2*(adj@t1)+gb1) ----------------
  if (tid < 768) {
    const int br = wid >> 2, mt = wid & 3;
    const int j15 = l & 15, kg4 = (l >> 4) * 4;
    float rinv2;
    {
      const unsigned short* rp = adjw + (br * 64 + mt * 16 + j15) * 72 + (l >> 4) * 16;
      u32x4 v0 = *(const u32x4*)rp;
      u32x4 v1 = *(const u32x4*)(rp + 8);
      unsigned wds[8] = {v0.x, v0.y, v0.z, v0.w, v1.x, v1.y, v1.z, v1.w};
      float s = 0.f;
#pragma unroll
      for (int e = 0; e < 8; ++e) {
        s += __uint_as_float(wds[e] << 16);
        s += __uint_as_float(wds[e] & 0xFFFF0000u);
      }
      s += __shfl_xor(s, 16);
      s += __shfl_xor(s, 32);
      rinv2 = 1.0f / s;
      if (l < 16) rinv2_s[br][mt * 16 + l] = rinv2;  // for B5
    }
    float rv4[4];
#pragma unroll
    for (int r = 0; r < 4; ++r) rv4[r] = __shfl(rinv2, (l >> 4) * 4 + r);

    const int arow = br * 64 + mt * 16 + j15;
    f32x4 acc = (f32x4)0.f;
#pragma unroll
    for (int ks = 0; ks < 2; ++ks) {
      int kb = ks * 32;
      u32x2 lo = *(const u32x2*)(adjw + arow * 72 + kb + kg4);
      u32x2 hi = *(const u32x2*)(adjw + arow * 72 + kb + 16 + kg4);
      u32x4 cc; cc.x = lo.x; cc.y = lo.y; cc.z = hi.x; cc.w = hi.y;
      short8 af = __builtin_bit_cast(short8, cc);
      float4 b0 = *(const float4*)(t1T + (br * 8 + j15) * AS + kb + kg4);
      float4 b1 = *(const float4*)(t1T + (br * 8 + j15) * AS + kb + 16 + kg4);
      short8 bh, bm, bl;
      split3(b0, b1, bh, bm, bl);
      acc = mm16(af, bh, acc); acc = mm16(af, bm, acc); acc = mm16(af, bl, acc);
    }
    if (j15 < 8) {
      float g1 = gb1s[j15];
#pragma unroll
      for (int r = 0; r < 4; ++r) {
        int n = mt * 16 + (l >> 4) * 4 + r;
        hT[(br * 8 + j15) * AS + n] = fmaxf(fmaf(acc[r], rv4[r], g1), 0.0f);
      }
    }
  }
  __syncthreads();

  // ---------------- B5: g = rinv2*(adj@h) ----------------
  if (tid < 768) {
    const int br = wid >> 2, mt = wid & 3;
    const int j15 = l & 15, kg4 = (l >> 4) * 4;
    const int arow = br * 64 + mt * 16 + j15;
    f32x4 acc = (f32x4)0.f;
#pragma unroll
    for (int ks = 0; ks < 2; ++ks) {
      int kb = ks * 32;
      u32x2 lo = *(const u32x2*)(adjw + arow * 72 + kb + kg4);
      u32x2 hi = *(const u32x2*)(adjw + arow * 72 + kb + 16 + kg4);
      u32x4 cc; cc.x = lo.x; cc.y = lo.y; cc.z = hi.x; cc.w = hi.y;
      short8 af = __builtin_bit_cast(short8, cc);
      float4 b0 = *(const float4*)(hT + (br * 8 + j15) * AS + kb + kg4);
      float4 b1 = *(const float4*)(hT + (br * 8 + j15) * AS + kb + 16 + kg4);
      short8 bh, bm, bl;
      split3(b0, b1, bh, bm, bl);
      acc = mm16(af, bh, acc); acc = mm16(af, bm, acc); acc = mm16(af, bl, acc);
    }
    if (j15 < 8) {
#pragma unroll
      for (int r = 0; r < 4; ++r) {
        int n = mt * 16 + (l >> 4) * 4 + r;
        gsm[(br * 64 + n) * 8 + j15] = acc[r] * rinv2_s[br][n];
      }
    }
  }
  __syncthreads();

  // ---------------- B6: f = g @ gw2 + gb2 (vector, gw2 from L2) ----------------
  {
    int n0 = tid >> 5, hq = tid & 31;
    float4 wreg[8];
#pragma unroll
    for (int j = 0; j < 8; ++j) wreg[j] = ((const float4*)gw2)[j * 32 + hq];
    float4 bquad = ((const float4*)gb2s)[hq];
#pragma unroll
    for (int br = 0; br < 3; ++br) {
      float4* f4b = (br == 0) ? fq4 : (br == 1) ? fk4 : fv4;
#pragma unroll
      for (int half = 0; half < 2; ++half) {
        int n = n0 + 32 * half;
        const float* g = gsm + (br * 64 + n) * 8;
        float4 g0 = *(const float4*)g;
        float4 g1 = *(const float4*)(g + 4);
        float4 a = bquad;
        fma4(a, g0.x, wreg[0]); fma4(a, g0.y, wreg[1]); fma4(a, g0.z, wreg[2]); fma4(a, g0.w, wreg[3]);
        fma4(a, g1.x, wreg[4]); fma4(a, g1.y, wreg[5]); fma4(a, g1.z, wreg[6]); fma4(a, g1.w, wreg[7]);
        f4b[n * FSQ + hq] = a;
      }
    }
  }
  __syncthreads();

  // ---------------- C0: kT build ----------------
  float* kT = U;             // 128*68
  float* Pp = U + 8704;      // [2][25][64]
  {
    const int c = tid >> 6;
    const int n = tid & 63;
    float4 v0 = fk4[n * FSQ + 2 * c];
    float4 v1 = fk4[n * FSQ + 2 * c + 1];
    const float* p0 = (const float*)&v0;
    const float* p1 = (const float*)&v1;
#pragma unroll
    for (int e = 0; e < 4; ++e) kT[(8 * c + e) * AS + n] = p0[e];
#pragma unroll
    for (int e = 0; e < 4; ++e) kT[(8 * c + 4 + e) * AS + n] = p1[e];
  }
  __syncthreads();

  // ---------------- C1: qk_sample b64 n-pair gathers, static indices (waves 0-1)
  //                      || cumsum all rows (waves 2-3) ----------------
  const float gamma = *gammap;
  if (tid < 128) {
    const int w = wid;            // l-half: w*64 .. w*64+63, sequential
    const int na = l & 31;        // n pair (2na, 2na+1)
    const bool lo = ((l >> 5) == 0);  // s-half: lanes 0-31 -> s 0..12, lanes 32-63 -> s 13..24
    float acc0[13], acc1[13];
#pragma unroll
    for (int si = 0; si < 13; ++si) { acc0[si] = 0.f; acc1[si] = 0.f; }
    const float* q0 = fq + (2 * na) * FS + w * 64;
    const float* q1 = q0 + FS;
    for (int lb = 0; lb < 16; ++lb) {
      float4 qa = *(const float4*)(q0 + 4 * lb);
      float4 qb = *(const float4*)(q1 + 4 * lb);
      const float qs0[4] = {qa.x, qa.y, qa.z, qa.w};
      const float qs1[4] = {qb.x, qb.y, qb.z, qb.w};
#pragma unroll
      for (int i = 0; i < 4; ++i) {
        const int base = __builtin_amdgcn_readfirstlane((w * 64 + 4 * lb + i) * 25);
        const float qv0 = qs0[i], qv1 = qs1[i];
#pragma unroll
        for (int si = 0; si < 13; ++si) {
          int klo = idxg[base + si];                       // s_load (static offset)
          int khi = (si < 12) ? idxg[base + 13 + si] : 0;  // s_load (static offset)
          int ki = lo ? klo : khi;                         // value select, no array indexing
          float2 kv = *(const float2*)(kT + ki * AS + 2 * na);
          if (si < 12) {
            acc0[si] = fmaf(qv0, kv.x, acc0[si]);
            acc1[si] = fmaf(qv1, kv.y, acc1[si]);
          } else if (lo) {
            acc0[12] = fmaf(qv0, kv.x, acc0[12]);
            acc1[12] = fmaf(qv1, kv.y, acc1[12]);
          }
        }
      }
    }
#pragma unroll
    for (int si = 0; si < 13; ++si) {
      int s = lo ? si : 13 + si;
      if (si < 12 || lo) {
        float2 pr; pr.x = acc0[si]; pr.y = acc1[si];
        *(float2*)(Pp + (w * 25 + s) * 64 + 2 * na) = pr;
      }
    }
  } else if (tid < 256) {
    const int h = tid - 128;
    float acc = 0.f;
    for (int n = 0; n < 64; ++n) {
      acc += fv[n * FS + h];
      outb[n * 128 + h] = fmaf(gamma, acc, xb[n * 128 + h]);
    }
  }
  __syncthreads();

  // ---------------- C2: M + top-25 (wave 0) || vT build (waves 2-15) ----------------
  float* vT = U;             // 128*68 (kT dead)
  if (tid < 64) {
    if (tid >= 25 && tid < 32) mte[tid] = 0;
    const float* P0 = Pp;
    const float* P1 = Pp + 1600;
    float mx = -INFINITY, su = 0.f;
#pragma unroll
    for (int s = 0; s < 25; ++s) {
      float vsum = P0[s * 64 + tid] + P1[s * 64 + tid];
      mx = fmaxf(mx, vsum);
      su += vsum;
    }
    float v = mx - su * (1.0f / 128.0f);
    for (int it = 0; it < 25; ++it) {
      float bv2 = v;
      int bi = tid;
#pragma unroll
      for (int off = 32; off > 0; off >>= 1) {
        float ov = __shfl_xor(bv2, off);
        int oi = __shfl_xor(bi, off);
        if (ov > bv2 || (ov == bv2 && oi < bi)) { bv2 = ov; bi = oi; }
      }
      if (tid == 0) mte[it] = bi;
      if (tid == bi) v = -INFINITY;
    }
  } else if (tid >= 128) {
    for (int i = tid - 128; i < 8192; i += 896) {
      int h2 = i >> 6, n = i & 63;
      vT[h2 * AS + n] = fv[n * FS + h2];
    }
  }
  __syncthreads();

  // ---------------- C3: dense scores MFMA (waves 0-1, split2) ----------------
  float* sc = U + 8704;      // 25*68 (Pp dead)
  if (tid < 128) {
    const int wsc = wid;
    const int lr = l & 31;
    const int kg = (l >> 5) * 4;
    const int qr = mte[lr];
    const float scale = 0.08838834764831845f;
    f32x16 acc = (f32x16)0.f;
    for (int ks = 0; ks < 8; ++ks) {
      int kb = ks * 16;
      float4 a0 = *(const float4*)(fq + qr * FS + kb + kg);
      float4 a1 = *(const float4*)(fq + qr * FS + kb + 8 + kg);
      float4 b0 = *(const float4*)(fk + (wsc * 32 + lr) * FS + kb + kg);
      float4 b1 = *(const float4*)(fk + (wsc * 32 + lr) * FS + kb + 8 + kg);
      short8 ah, al2, bh, bl;
      split2(a0, a1, ah, al2);
      split2(b0, b1, bh, bl);
      acc = mm32(ah, bh, acc);
      acc = mm32(ah, bl, acc);
      acc = mm32(al2, bh, acc);
    }
#pragma unroll
    for (int reg = 0; reg < 16; ++reg) {
      int uu = (reg & 3) + 8 * (reg >> 2) + 4 * (l >> 5);
      if (uu < 25) sc[uu * AS + wsc * 32 + lr] = acc[reg] * scale;
    }
  }
  __syncthreads();

  // ---------------- C4: softmax over n (16 lanes per selected row) ----------------
  if (tid < 400) {
    int u = tid >> 4, g = tid & 15;
    float4* s4 = (float4*)(sc + u * AS);
    float4 v = s4[g];
    float mx = fmaxf(fmaxf(v.x, v.y), fmaxf(v.z, v.w));
    for (int off = 8; off; off >>= 1) mx = fmaxf(mx, __shfl_xor(mx, off));
    float4 e;
    e.x = __expf(v.x - mx); e.y = __expf(v.y - mx);
    e.z = __expf(v.z - mx); e.w = __expf(v.w - mx);
    float su = e.x + e.y + e.z + e.w;
    for (int off = 8; off; off >>= 1) su += __shfl_xor(su, off);
    float inv = 1.0f / su;
    e.x *= inv; e.y *= inv; e.z *= inv; e.w *= inv;
    s4[g] = e;
  }
  __syncthreads();

  // ---------------- C5: upd MFMA: out[mte[u]] = gamma*(attn@v) + x ----------------
  if (tid < 512) {
    const int w8 = wid;
    const int li = l & 15;
    const int kg4 = (l >> 4) * 4;
#pragma unroll
    for (int i = 0; i < 2; ++i) {
      int t = w8 * 2 + i;
      int ut = t >> 3, ht = t & 7;
      int u = ut * 16 + li;
      f32x4 acc = (f32x4)0.f;
#pragma unroll
      for (int ks = 0; ks < 2; ++ks) {
        int kb = ks * 32;
        float4 a0 = *(const float4*)(sc + u * AS + kb + kg4);
        float4 a1 = *(const float4*)(sc + u * AS + kb + 16 + kg4);
        float4 b0 = *(const float4*)(vT + (ht * 16 + li) * AS + kb + kg4);
        float4 b1 = *(const float4*)(vT + (ht * 16 + li) * AS + kb + 16 + kg4);
        short8 ah, al2, bh, bl;
        split2(a0, a1, ah, al2);
        split2(b0, b1, bh, bl);
        acc = mm16(ah, bh, acc);
        acc = mm16(ah, bl, acc);
        acc = mm16(al2, bh, acc);
      }
      int hcol = ht * 16 + li;
#pragma unroll
      for (int r = 0; r < 4; ++r) {
        int uu = ut * 16 + (l >> 4) * 4 + r;
        if (uu < 25) {
          int row = mte[uu];
          int o = row * 128 + hcol;
          outb[o] = fmaf(gamma, acc[r], xb[o]);
        }
      }
    }
  }
}

extern "C" void kernel_launch(void* const* d_in, const int* in_sizes, int n_in,
                              void* d_out, int out_size, void* d_ws, size_t ws_size,
                              hipStream_t stream) {
  const float* x   = (const float*)d_in[0];
  const float* wq  = (const float*)d_in[1];
  const float* bq  = (const float*)d_in[2];
  const float* wk  = (const float*)d_in[3];
  const float* bk  = (const float*)d_in[4];
  const float* wv  = (const float*)d_in[5];
  const float* bv  = (const float*)d_in[6];
  const float* gw1 = (const float*)d_in[7];
  const float* gb1 = (const float*)d_in[8];
  const float* gw2 = (const float*)d_in[9];
  const float* gb2 = (const float*)d_in[10];
  const float* gm  = (const float*)d_in[11];
  const int* idx   = (const int*)d_in[12];
  float* out = (float*)d_out;
  int B = in_sizes[0] / (64 * 128);
  hipLaunchKernelGGL(gcn_ssa_kernel, dim3(B), dim3(T), 0, stream,
                     x, wq, bq, wk, bk, wv, bv, gw1, gb1, gw2, gb2, gm, idx, out);
}